// Round 6
// baseline (722.538 us; speedup 1.0000x reference)
//
#include <hip/hip_runtime.h>

#define T_TOK 2048
#define TOPK  8
#define NEXP  32
#define HDIM  1024
#define IDIM  768
#define NPAIR (T_TOK * TOPK)   // 16384
#define BM 128
#define BK 32
#define MT_MAX (NPAIR / BM + NEXP)  // 160 upper bound on sum(ceil(Me/BM))

typedef __attribute__((ext_vector_type(8))) short short8;   // 8 x bf16 (4 VGPRs)
typedef __attribute__((ext_vector_type(4))) float f32x4;    // MFMA accumulator

__device__ __forceinline__ unsigned short f2bf(float f) {
    unsigned x = __float_as_uint(f);
    unsigned r = x + 0x7fffu + ((x >> 16) & 1u);
    return (unsigned short)(r >> 16);
}
__device__ __forceinline__ float bf2f(unsigned short u) {
    return __uint_as_float(((unsigned)u) << 16);
}

// XCD swizzle: runs of 2 consecutive m-tiles per XCD (weight-panel L2 reuse).
// Bijective on [0,160); proven: FETCH_SIZE 238->156 MB in round 1.
__device__ __forceinline__ int mt_swz(int bx) {
    return ((bx >> 4) << 4) | ((bx & 7) << 1) | ((bx >> 3) & 1);
}

// ---------------- fp32 -> bf16 convert (two tensors, contiguous dst) ----------------
__global__ void k_conv2(const float* __restrict__ src0, const float* __restrict__ src1,
                        unsigned short* __restrict__ dst, int n4each) {
    int i = blockIdx.x * 256 + threadIdx.x;
    const float* s = (i < n4each) ? src0 : src1;
    int j = (i < n4each) ? i : i - n4each;
    if (i < 2 * n4each) {
        float4 v = ((const float4*)s)[j];
        ushort4 o;
        o.x = f2bf(v.x); o.y = f2bf(v.y); o.z = f2bf(v.z); o.w = f2bf(v.w);
        ((ushort4*)dst)[i] = o;
    }
}

__global__ void k_conv(const float* __restrict__ src, unsigned short* __restrict__ dst, int n4) {
    int i = blockIdx.x * 256 + threadIdx.x;
    if (i < n4) {
        float4 v = ((const float4*)src)[i];
        ushort4 o;
        o.x = f2bf(v.x); o.y = f2bf(v.y); o.z = f2bf(v.z); o.w = f2bf(v.w);
        ((ushort4*)dst)[i] = o;
    }
}

// ---------------- routing kernels ----------------
__global__ void k_init(int* counts) {
    if (threadIdx.x < NEXP) counts[threadIdx.x] = 0;
}

__global__ void k_hist(const int* __restrict__ idx, int* __restrict__ counts) {
    int p = blockIdx.x * 256 + threadIdx.x;
    atomicAdd(&counts[idx[p]], 1);
}

__global__ void k_scan(const int* __restrict__ counts, int* __restrict__ offsets,
                       int* __restrict__ mtb, int* __restrict__ cursor) {
    if (threadIdx.x == 0) {
        int tot = 0, mt = 0;
        for (int e = 0; e < NEXP; ++e) {
            offsets[e] = tot; mtb[e] = mt;
            tot += counts[e];
            mt += (counts[e] + BM - 1) / BM;
        }
        offsets[NEXP] = tot; mtb[NEXP] = mt;
    }
    if (threadIdx.x < NEXP) cursor[threadIdx.x] = 0;
}

__global__ void k_scatter(const int* __restrict__ idx, int* __restrict__ cursor,
                          const int* __restrict__ offsets, int* __restrict__ pair_token,
                          int* __restrict__ pair_slot) {
    int p = blockIdx.x * 256 + threadIdx.x;
    int e = idx[p];
    int pos = atomicAdd(&cursor[e], 1);
    int slot = offsets[e] + pos;
    pair_token[slot] = p >> 3;   // p / TOPK
    pair_slot[p] = slot;
}

// ---------------- gate+up fused GEMM + SwiGLU (no-LDS, frags direct from global) ----
// BM=128, BN=64 (dual tensor), BK=32. 4 waves 2x2; wave-tile 64(m) x 32(n) per tensor.
// Fragment sourcing (identical math to the verified LDS-slot mapping):
//   A: lane(quad,l16) = hid[tok(row)][k0+quad*8..+8], row = wm+fm*16+l16
//   B: lane(quad,l16) = w[e][n0+wn+fn*16+l16][k0+quad*8..+8]
// Two named register sets -> 1-step software pipeline; compiler manages vmcnt.
__global__ __launch_bounds__(256, 3) void k_gateup(
    const unsigned short* __restrict__ hid_bf, const unsigned short* __restrict__ gate_bf,
    const unsigned short* __restrict__ up_bf, const int* __restrict__ pair_token,
    const int* __restrict__ offsets, const int* __restrict__ mtb,
    unsigned short* __restrict__ h_mid)
{
    __shared__ int sInfo[4];
    int tid = threadIdx.x;
    int mt = mt_swz(blockIdx.x);
    if (tid == 0 && mt >= mtb[NEXP]) sInfo[0] = -1;
    if (tid < NEXP) {                      // parallel expert search
        int lo = mtb[tid], hi = mtb[tid + 1];
        if (lo <= mt && mt < hi) {
            sInfo[0] = tid; sInfo[1] = offsets[tid];
            sInfo[2] = offsets[tid + 1] - offsets[tid];
            sInfo[3] = (mt - lo) * BM;
        }
    }
    __syncthreads();
    int e = sInfo[0];
    if (e < 0) return;
    int off = sInfo[1], Me = sInfo[2], mrow0 = sInfo[3];
    int n0 = blockIdx.y * 64;

    int wave = tid >> 6, lane = tid & 63, quad = lane >> 4, l16 = lane & 15;
    int wm = (wave & 1) * 64, wn = (wave >> 1) * 32;

    // A pointers: 4 token rows per lane (gathered via pair_token, clamped)
    const unsigned short* aP[4];
#pragma unroll
    for (int fm = 0; fm < 4; ++fm) {
        int rp = mrow0 + wm + fm * 16 + l16;
        int tok = pair_token[off + ((rp < Me) ? rp : (Me - 1))];
        aP[fm] = hid_bf + (size_t)tok * HDIM + quad * 8;
    }
    // B pointers: 2 gate rows + 2 up rows per lane
    const unsigned short* gP[2];
    const unsigned short* uP[2];
#pragma unroll
    for (int fn = 0; fn < 2; ++fn) {
        size_t row = (size_t)e * IDIM + n0 + wn + fn * 16 + l16;
        gP[fn] = gate_bf + row * HDIM + quad * 8;
        uP[fn] = up_bf   + row * HDIM + quad * 8;
    }

    f32x4 zero = {0.f, 0.f, 0.f, 0.f};
    f32x4 accg[4][2], accu[4][2];
#pragma unroll
    for (int i = 0; i < 4; ++i)
#pragma unroll
        for (int j = 0; j < 2; ++j) { accg[i][j] = zero; accu[i][j] = zero; }

    short8 A0[4], G0[2], U0[2], A1[4], G1[2], U1[2];

#define LDALL_GU(A_, G_, U_, kk) do { \
        _Pragma("unroll") for (int i = 0; i < 4; ++i) A_[i] = *(const short8*)(aP[i] + (kk)); \
        _Pragma("unroll") for (int i = 0; i < 2; ++i) G_[i] = *(const short8*)(gP[i] + (kk)); \
        _Pragma("unroll") for (int i = 0; i < 2; ++i) U_[i] = *(const short8*)(uP[i] + (kk)); \
    } while (0)

#define FMA_GU(A_, G_, U_) do { \
        _Pragma("unroll") for (int fn = 0; fn < 2; ++fn) \
            _Pragma("unroll") for (int fm = 0; fm < 4; ++fm) { \
                accg[fm][fn] = __builtin_amdgcn_mfma_f32_16x16x32_bf16(A_[fm], G_[fn], accg[fm][fn], 0, 0, 0); \
                accu[fm][fn] = __builtin_amdgcn_mfma_f32_16x16x32_bf16(A_[fm], U_[fn], accu[fm][fn], 0, 0, 0); \
            } \
    } while (0)

    LDALL_GU(A0, G0, U0, 0);
#pragma unroll 1
    for (int k0 = 0; k0 < HDIM - 64; k0 += 64) {
        LDALL_GU(A1, G1, U1, k0 + 32);
        FMA_GU(A0, G0, U0);
        LDALL_GU(A0, G0, U0, k0 + 64);
        FMA_GU(A1, G1, U1);
    }
    LDALL_GU(A1, G1, U1, HDIM - 32);
    FMA_GU(A0, G0, U0);
    FMA_GU(A1, G1, U1);

    // epilogue: silu(g)*u -> bf16 h_mid   (C/D: row=(lane>>4)*4+reg, col=lane&15)
#pragma unroll
    for (int fm = 0; fm < 4; ++fm)
#pragma unroll
        for (int fn = 0; fn < 2; ++fn)
#pragma unroll
            for (int r = 0; r < 4; ++r) {
                int mloc = wm + fm * 16 + quad * 4 + r;
                int prow = mrow0 + mloc;
                if (prow < Me) {
                    int col = n0 + wn + fn * 16 + l16;
                    float g = accg[fm][fn][r], u = accu[fm][fn][r];
                    float h = g / (1.f + __expf(-g)) * u;
                    h_mid[(size_t)(off + prow) * IDIM + col] = f2bf(h);
                }
            }
}

// ---------------- down GEMM (no-LDS, frags direct from global) ----------------
// BM=128, BN=128, BK=32. 4 waves 2x2; wave-tile 64(m) x 64(n); frags 4x4; acc 64.
__global__ __launch_bounds__(256, 3) void k_down(
    const unsigned short* __restrict__ h_mid, const unsigned short* __restrict__ down_bf,
    const int* __restrict__ offsets, const int* __restrict__ mtb,
    unsigned short* __restrict__ y_pair)
{
    __shared__ int sInfo[4];
    int tid = threadIdx.x;
    int mt = mt_swz(blockIdx.x);
    if (tid == 0 && mt >= mtb[NEXP]) sInfo[0] = -1;
    if (tid < NEXP) {
        int lo = mtb[tid], hi = mtb[tid + 1];
        if (lo <= mt && mt < hi) {
            sInfo[0] = tid; sInfo[1] = offsets[tid];
            sInfo[2] = offsets[tid + 1] - offsets[tid];
            sInfo[3] = (mt - lo) * BM;
        }
    }
    __syncthreads();
    int e = sInfo[0];
    if (e < 0) return;
    int off = sInfo[1], Me = sInfo[2], mrow0 = sInfo[3];
    int n0 = blockIdx.y * 128;

    int wave = tid >> 6, lane = tid & 63, quad = lane >> 4, l16 = lane & 15;
    int wm = (wave & 1) * 64, wn = (wave >> 1) * 64;

    const unsigned short* aP[4];
#pragma unroll
    for (int fm = 0; fm < 4; ++fm) {
        int rp = mrow0 + wm + fm * 16 + l16;
        if (rp >= Me) rp = Me - 1;
        aP[fm] = h_mid + (size_t)(off + rp) * IDIM + quad * 8;
    }
    const unsigned short* bP[4];
#pragma unroll
    for (int fn = 0; fn < 4; ++fn)
        bP[fn] = down_bf + ((size_t)e * HDIM + n0 + wn + fn * 16 + l16) * IDIM + quad * 8;

    f32x4 zero = {0.f, 0.f, 0.f, 0.f};
    f32x4 acc[4][4];
#pragma unroll
    for (int i = 0; i < 4; ++i)
#pragma unroll
        for (int j = 0; j < 4; ++j) acc[i][j] = zero;

    short8 A0[4], B0[4], A1[4], B1[4];

#define LDALL_DN(A_, B_, kk) do { \
        _Pragma("unroll") for (int i = 0; i < 4; ++i) A_[i] = *(const short8*)(aP[i] + (kk)); \
        _Pragma("unroll") for (int i = 0; i < 4; ++i) B_[i] = *(const short8*)(bP[i] + (kk)); \
    } while (0)

#define FMA_DN(A_, B_) do { \
        _Pragma("unroll") for (int fn = 0; fn < 4; ++fn) \
            _Pragma("unroll") for (int fm = 0; fm < 4; ++fm) \
                acc[fm][fn] = __builtin_amdgcn_mfma_f32_16x16x32_bf16(A_[fm], B_[fn], acc[fm][fn], 0, 0, 0); \
    } while (0)

    LDALL_DN(A0, B0, 0);
#pragma unroll 1
    for (int k0 = 0; k0 < IDIM - 64; k0 += 64) {
        LDALL_DN(A1, B1, k0 + 32);
        FMA_DN(A0, B0);
        LDALL_DN(A0, B0, k0 + 64);
        FMA_DN(A1, B1);
    }
    LDALL_DN(A1, B1, IDIM - 32);
    FMA_DN(A0, B0);
    FMA_DN(A1, B1);

#pragma unroll
    for (int fm = 0; fm < 4; ++fm)
#pragma unroll
        for (int fn = 0; fn < 4; ++fn)
#pragma unroll
            for (int r = 0; r < 4; ++r) {
                int mloc = wm + fm * 16 + quad * 4 + r;
                int prow = mrow0 + mloc;
                if (prow < Me) {
                    int col = n0 + wn + fn * 16 + l16;
                    y_pair[(size_t)(off + prow) * HDIM + col] = f2bf(acc[fm][fn][r]);
                }
            }
}

// ---------------- per-token weighted reduce ----------------
__global__ void k_reduce(const unsigned short* __restrict__ y_pair,
                         const int* __restrict__ pair_slot,
                         const float* __restrict__ topw, float* __restrict__ out)
{
    int t = blockIdx.x;
    __shared__ int ss[TOPK];
    __shared__ float sw[TOPK];
    if (threadIdx.x < TOPK) {
        ss[threadIdx.x] = pair_slot[t * TOPK + threadIdx.x];
        sw[threadIdx.x] = topw[t * TOPK + threadIdx.x];
    }
    __syncthreads();
    int c = threadIdx.x * 4;
    float a0 = 0.f, a1 = 0.f, a2 = 0.f, a3 = 0.f;
    for (int k = 0; k < TOPK; ++k) {
        const unsigned short* yr = y_pair + (size_t)ss[k] * HDIM + c;
        uint2 v = *(const uint2*)yr;
        float w = sw[k];
        a0 += w * bf2f((unsigned short)(v.x & 0xffff));
        a1 += w * bf2f((unsigned short)(v.x >> 16));
        a2 += w * bf2f((unsigned short)(v.y & 0xffff));
        a3 += w * bf2f((unsigned short)(v.y >> 16));
    }
    float4 o = {a0, a1, a2, a3};
    *(float4*)(out + (size_t)t * HDIM + c) = o;
}

extern "C" void kernel_launch(void* const* d_in, const int* in_sizes, int n_in,
                              void* d_out, int out_size, void* d_ws, size_t ws_size,
                              hipStream_t stream) {
    (void)in_sizes; (void)n_in; (void)out_size; (void)ws_size;
    const float* hidden = (const float*)d_in[0];
    const int*   tki    = (const int*)d_in[1];
    const float* tkw    = (const float*)d_in[2];
    const float* gate   = (const float*)d_in[3];
    const float* up     = (const float*)d_in[4];
    const float* down   = (const float*)d_in[5];
    float* out = (float*)d_out;

    // ws layout (131 MB):
    //   [0]            h_mid   25,165,824 B  (live: gateup -> down)
    //   [25,165,824]   hid_bf   4,194,304 B  (live: conv -> gateup)
    //   [29,360,128]   region1 50,331,648 B  gate_bf; later down_bf (after gateup)
    //   [79,691,776]   region2 50,331,648 B  up_bf;   later y_pair  (after gateup)
    //   [130,023,424]  int scratch
    char* w = (char*)d_ws;
    unsigned short* h_mid   = (unsigned short*)w;
    unsigned short* hid_bf  = (unsigned short*)(w + 25165824);
    unsigned short* gate_bf = (unsigned short*)(w + 29360128);
    unsigned short* up_bf   = (unsigned short*)(w + 79691776);
    unsigned short* down_bf = gate_bf;   // aliases gate_bf after k_gateup completes
    unsigned short* y_pair  = up_bf;     // aliases up_bf   after k_gateup completes
    int* ib = (int*)(w + 130023424);
    int* pair_token = ib;                // NPAIR
    int* pair_slot  = ib + NPAIR;        // NPAIR
    int* counts     = ib + 2 * NPAIR;    // NEXP
    int* cursor     = counts + NEXP;     // NEXP
    int* offsets    = cursor + NEXP;     // NEXP+1
    int* mtb        = offsets + NEXP + 1;// NEXP+1

    const int W4 = NEXP * IDIM * HDIM / 4;   // 6,291,456 float4 per weight tensor
    const int H4 = T_TOK * HDIM / 4;         // 524,288

    k_init<<<1, 64, 0, stream>>>(counts);
    k_hist<<<NPAIR / 256, 256, 0, stream>>>(tki, counts);
    k_scan<<<1, 64, 0, stream>>>(counts, offsets, mtb, cursor);
    k_scatter<<<NPAIR / 256, 256, 0, stream>>>(tki, cursor, offsets, pair_token, pair_slot);

    k_conv<<<(H4 + 255) / 256, 256, 0, stream>>>(hidden, hid_bf, H4);
    k_conv2<<<(2 * W4 + 255) / 256, 256, 0, stream>>>(gate, up, gate_bf, W4);

    k_gateup<<<dim3(MT_MAX, IDIM / 64), 256, 0, stream>>>(hid_bf, gate_bf, up_bf,
                                                          pair_token, offsets, mtb, h_mid);

    k_conv<<<(W4 + 255) / 256, 256, 0, stream>>>(down, down_bf, W4);

    k_down<<<dim3(MT_MAX, HDIM / 128), 256, 0, stream>>>(h_mid, down_bf, offsets, mtb, y_pair);
    k_reduce<<<T_TOK, 256, 0, stream>>>(y_pair, pair_slot, tkw, out);
}